// Round 3
// baseline (12570.039 us; speedup 1.0000x reference)
//
#include <hip/hip_runtime.h>
#include <hip/hip_bf16.h>

typedef __hip_bfloat16 bf16;
typedef __hip_bfloat162 bf162;

#define NB 4
#define NC 512
#define NQ 64
#define NN 4096
#define QT 4
#define TCO 8

// ---------------------------------------------------------------------------
// 1x1 conv: out[b, co, n] = sum_c W[co,c] * X[b,c,n] + bias[co]
// TCO=8 output channels per block (W rows staged in LDS, 16KB) so each X
// element loaded once per 8 channels. Each thread: 8 consecutive n (2 float4).
// grid: (NN/2048, Co/TCO, NB), block 256.
// ---------------------------------------------------------------------------
template <typename OutT>
__global__ __launch_bounds__(256) void proj_kernel(
    const float* __restrict__ X, const float* __restrict__ Wf,
    const float* __restrict__ bias, OutT* __restrict__ out, int Co) {
  __shared__ float lw[TCO][NC];
  __shared__ float lb[TCO];
  int b   = blockIdx.z;
  int co0 = blockIdx.y * TCO;
  int tid = threadIdx.x;

  for (int idx = tid; idx < TCO * NC; idx += 256) {
    int r = idx >> 9, c = idx & (NC - 1);
    lw[r][c] = Wf[(size_t)(co0 + r) * NC + c];
  }
  if (tid < TCO) lb[tid] = bias[co0 + tid];
  __syncthreads();

  int n0 = (blockIdx.x * 256 + tid) * 8;
  const float* xp = X + (size_t)b * NC * NN + n0;

  float acc[TCO][8];
#pragma unroll
  for (int ci = 0; ci < TCO; ++ci)
#pragma unroll
    for (int i = 0; i < 8; ++i) acc[ci][i] = lb[ci];

#pragma unroll 2
  for (int c = 0; c < NC; ++c) {
    float4 x0 = *reinterpret_cast<const float4*>(xp + (size_t)c * NN);
    float4 x1 = *reinterpret_cast<const float4*>(xp + (size_t)c * NN + 4);
    float xs[8] = {x0.x, x0.y, x0.z, x0.w, x1.x, x1.y, x1.z, x1.w};
#pragma unroll
    for (int ci = 0; ci < TCO; ++ci) {
      float w = lw[ci][c];  // uniform LDS address -> broadcast
#pragma unroll
      for (int i = 0; i < 8; ++i) acc[ci][i] += w * xs[i];
    }
  }

#pragma unroll
  for (int ci = 0; ci < TCO; ++ci) {
    OutT* op = out + ((size_t)b * Co + co0 + ci) * NN + n0;
#pragma unroll
    for (int i = 0; i < 8; ++i) op[i] = (OutT)acc[ci][i];
  }
}

// ---------------------------------------------------------------------------
// Attention: one block handles (b, QT=4 queries).  256 threads = 4 waves.
// Phase 1: energies for all m, packed bf16 in 32KB LDS.
// Phase 2: two-pass softmax (block max, exp+sum).
// Phase 3: out[b,c,nq] = gamma * (sum_m p[m]*v[c,m]) / denom + x[b,c,nq].
// grid: (NN/QT, NB), block 256.
// ---------------------------------------------------------------------------
__global__ __launch_bounds__(256) void attn_kernel(
    const float* __restrict__ qf, const bf16* __restrict__ kf,
    const bf16* __restrict__ vf, const float* __restrict__ x,
    const float* __restrict__ gamma, float* __restrict__ out0) {
  __shared__ bf162 elds[NN * 2];  // [m][4q] packed as 2 x bf162 -> 32KB
  __shared__ float red[16];       // 4 waves x 4 queries

  int tid  = threadIdx.x;
  int lane = tid & 63;
  int wave = tid >> 6;
  int b    = blockIdx.y;
  int nq0  = blockIdx.x * QT;

  const float* qp = qf + (size_t)b * NQ * NN + nq0;
  const bf16*  kp = kf + (size_t)b * NQ * NN;

  // ---- Phase 1: energies + running max -----------------------------------
  float pm0 = -3.0e38f, pm1 = -3.0e38f, pm2 = -3.0e38f, pm3 = -3.0e38f;
  for (int j = 0; j < 16; ++j) {
    int m = tid + j * 256;
    float a0 = 0.f, a1 = 0.f, a2 = 0.f, a3 = 0.f;
#pragma unroll 8
    for (int qi = 0; qi < NQ; ++qi) {
      float kv = __bfloat162float(kp[(size_t)qi * NN + m]);  // coalesced
      float q0 = qp[(size_t)qi * NN + 0];  // block-uniform
      float q1 = qp[(size_t)qi * NN + 1];
      float q2 = qp[(size_t)qi * NN + 2];
      float q3 = qp[(size_t)qi * NN + 3];
      a0 += q0 * kv; a1 += q1 * kv; a2 += q2 * kv; a3 += q3 * kv;
    }
    pm0 = fmaxf(pm0, a0); pm1 = fmaxf(pm1, a1);
    pm2 = fmaxf(pm2, a2); pm3 = fmaxf(pm3, a3);
    elds[m * 2]     = __float22bfloat162_rn(make_float2(a0, a1));
    elds[m * 2 + 1] = __float22bfloat162_rn(make_float2(a2, a3));
  }

  // ---- block max ----------------------------------------------------------
#pragma unroll
  for (int off = 32; off; off >>= 1) {
    pm0 = fmaxf(pm0, __shfl_xor(pm0, off));
    pm1 = fmaxf(pm1, __shfl_xor(pm1, off));
    pm2 = fmaxf(pm2, __shfl_xor(pm2, off));
    pm3 = fmaxf(pm3, __shfl_xor(pm3, off));
  }
  if (lane == 0) {
    red[wave * 4 + 0] = pm0; red[wave * 4 + 1] = pm1;
    red[wave * 4 + 2] = pm2; red[wave * 4 + 3] = pm3;
  }
  __syncthreads();
  float bm0 = fmaxf(fmaxf(red[0], red[4]), fmaxf(red[8], red[12]));
  float bm1 = fmaxf(fmaxf(red[1], red[5]), fmaxf(red[9], red[13]));
  float bm2 = fmaxf(fmaxf(red[2], red[6]), fmaxf(red[10], red[14]));
  float bm3 = fmaxf(fmaxf(red[3], red[7]), fmaxf(red[11], red[15]));

  // ---- Phase 2: exp + sum -------------------------------------------------
  const float L2E = 1.44269504f;
  float ps0 = 0.f, ps1 = 0.f, ps2 = 0.f, ps3 = 0.f;
  for (int j = 0; j < 16; ++j) {
    int m = tid + j * 256;
    float2 e01 = __bfloat1622float2(elds[m * 2]);
    float2 e23 = __bfloat1622float2(elds[m * 2 + 1]);
    float p0 = exp2f((e01.x - bm0) * L2E);
    float p1 = exp2f((e01.y - bm1) * L2E);
    float p2 = exp2f((e23.x - bm2) * L2E);
    float p3 = exp2f((e23.y - bm3) * L2E);
    ps0 += p0; ps1 += p1; ps2 += p2; ps3 += p3;
    elds[m * 2]     = __float22bfloat162_rn(make_float2(p0, p1));
    elds[m * 2 + 1] = __float22bfloat162_rn(make_float2(p2, p3));
  }
#pragma unroll
  for (int off = 32; off; off >>= 1) {
    ps0 += __shfl_xor(ps0, off);
    ps1 += __shfl_xor(ps1, off);
    ps2 += __shfl_xor(ps2, off);
    ps3 += __shfl_xor(ps3, off);
  }
  __syncthreads();  // everyone done reading red (max values)
  if (lane == 0) {
    red[wave * 4 + 0] = ps0; red[wave * 4 + 1] = ps1;
    red[wave * 4 + 2] = ps2; red[wave * 4 + 3] = ps3;
  }
  __syncthreads();  // publishes red sums and all elds p-writes
  float i0 = 1.f / (red[0] + red[4] + red[8] + red[12]);
  float i1 = 1.f / (red[1] + red[5] + red[9] + red[13]);
  float i2 = 1.f / (red[2] + red[6] + red[10] + red[14]);
  float i3 = 1.f / (red[3] + red[7] + red[11] + red[15]);

  // ---- Phase 3: out = gamma * (P @ V^T)/denom + x -------------------------
  const bf16*  vp = vf + (size_t)b * NC * NN;
  const float* xp = x + (size_t)b * NC * NN + nq0;
  float* op = out0 + (size_t)b * NC * NN + nq0;
  float g = gamma[0];

  for (int c0 = wave * 8; c0 < NC; c0 += 32) {
    float o[8][4];
#pragma unroll
    for (int ci = 0; ci < 8; ++ci)
#pragma unroll
      for (int q = 0; q < 4; ++q) o[ci][q] = 0.f;

    for (int mb = 0; mb < NN; mb += 64) {
      int m = mb + lane;
      float2 p01 = __bfloat1622float2(elds[m * 2]);
      float2 p23 = __bfloat1622float2(elds[m * 2 + 1]);
#pragma unroll
      for (int ci = 0; ci < 8; ++ci) {
        float vv = __bfloat162float(vp[(size_t)(c0 + ci) * NN + m]);
        o[ci][0] += vv * p01.x; o[ci][1] += vv * p01.y;
        o[ci][2] += vv * p23.x; o[ci][3] += vv * p23.y;
      }
    }
#pragma unroll
    for (int ci = 0; ci < 8; ++ci)
#pragma unroll
      for (int q = 0; q < 4; ++q) {
        float t = o[ci][q];
#pragma unroll
        for (int off = 32; off; off >>= 1) t += __shfl_xor(t, off);
        o[ci][q] = t;
      }
    if (lane == 0) {
#pragma unroll
      for (int ci = 0; ci < 8; ++ci) {
        float vals[4];
#pragma unroll
        for (int q = 0; q < 4; ++q) {
          float inv = (q == 0) ? i0 : (q == 1) ? i1 : (q == 2) ? i2 : i3;
          vals[q] = g * o[ci][q] * inv + xp[(size_t)(c0 + ci) * NN + q];
        }
#pragma unroll
        for (int q = 0; q < 4; ++q)
          op[(size_t)(c0 + ci) * NN + q] = vals[q];
      }
    }
  }
}

// ---------------------------------------------------------------------------
// out1 = x flattened (exact fp32 copy), 4 elements / thread.
// ---------------------------------------------------------------------------
__global__ __launch_bounds__(256) void copy_x(const float* __restrict__ x,
                                              float* __restrict__ out1) {
  size_t i = ((size_t)blockIdx.x * 256 + threadIdx.x) * 4;
  *reinterpret_cast<float4*>(out1 + i) =
      *reinterpret_cast<const float4*>(x + i);
}

extern "C" void kernel_launch(void* const* d_in, const int* in_sizes, int n_in,
                              void* d_out, int out_size, void* d_ws,
                              size_t ws_size, hipStream_t stream) {
  const float* x     = (const float*)d_in[0];
  // d_in[1] = style (unused by the reference)
  const float* skel  = (const float*)d_in[2];
  const float* Wq    = (const float*)d_in[3];
  const float* bq    = (const float*)d_in[4];
  const float* Wk    = (const float*)d_in[5];
  const float* bk    = (const float*)d_in[6];
  const float* Wv    = (const float*)d_in[7];
  const float* bv    = (const float*)d_in[8];
  const float* gamma = (const float*)d_in[9];

  // workspace (6 MB): qf [B][Cq][N] fp32 (4 MB) + kf [B][Cq][N] bf16 (2 MB).
  // vf [B][C][N] bf16 (16.8 MB) lives in the out1 half of d_out (33.5 MB in
  // fp32); attn only reads vf / writes out0, copy_x overwrites out1 after,
  // all stream-ordered.
  float* qf = (float*)d_ws;
  bf16*  kf = (bf16*)(qf + (size_t)NB * NQ * NN);

  float* out0 = (float*)d_out;
  float* out1 = out0 + (size_t)NB * NC * NN;
  bf16*  vf   = (bf16*)out1;  // scratch until copy_x runs

  proj_kernel<float><<<dim3(2, NQ / TCO, NB), dim3(256), 0, stream>>>(x, Wq, bq, qf, NQ);
  proj_kernel<bf16><<<dim3(2, NQ / TCO, NB), dim3(256), 0, stream>>>(skel, Wk, bk, kf, NQ);
  proj_kernel<bf16><<<dim3(2, NC / TCO, NB), dim3(256), 0, stream>>>(skel, Wv, bv, vf, NC);
  attn_kernel<<<dim3(NN / QT, NB), dim3(256), 0, stream>>>(qf, kf, vf, x, gamma, out0);
  copy_x<<<dim3(8192), dim3(256), 0, stream>>>(x, out1);
}

// Round 4
// 1077.075 us; speedup vs baseline: 11.6705x; 11.6705x over previous
//
#include <hip/hip_runtime.h>
#include <hip/hip_bf16.h>

typedef __hip_bfloat16 bf16;
typedef __hip_bfloat162 bf162;
typedef __attribute__((ext_vector_type(8))) short short8;
typedef __attribute__((ext_vector_type(16))) float floatx16;

#define NB 4
#define NC 512
#define CQ 64
#define NN 4096
#define TCO 8
#define LP 72  // LDS row pitch in bf16 (144B: 16B-aligned rows)

#define MFMA32 __builtin_amdgcn_mfma_f32_32x32x16_bf16

// ---------------------------------------------------------------------------
// 1x1 conv, output [co][n]: used for V. TCO=8 channels per block, W in LDS.
// grid: (NN/2048, Co/TCO, NB), block 256.
// ---------------------------------------------------------------------------
__global__ __launch_bounds__(256) void proj_kernel(
    const float* __restrict__ X, const float* __restrict__ Wf,
    const float* __restrict__ bias, bf16* __restrict__ out, int Co) {
  __shared__ float lw[TCO][NC];
  __shared__ float lb[TCO];
  int b = blockIdx.z, co0 = blockIdx.y * TCO, tid = threadIdx.x;

  for (int idx = tid; idx < TCO * NC; idx += 256) {
    int r = idx >> 9, c = idx & (NC - 1);
    lw[r][c] = Wf[(size_t)(co0 + r) * NC + c];
  }
  if (tid < TCO) lb[tid] = bias[co0 + tid];
  __syncthreads();

  int n0 = (blockIdx.x * 256 + tid) * 8;
  const float* xp = X + (size_t)b * NC * NN + n0;

  float acc[TCO][8];
#pragma unroll
  for (int ci = 0; ci < TCO; ++ci)
#pragma unroll
    for (int i = 0; i < 8; ++i) acc[ci][i] = lb[ci];

#pragma unroll 2
  for (int c = 0; c < NC; ++c) {
    float4 x0 = *reinterpret_cast<const float4*>(xp + (size_t)c * NN);
    float4 x1 = *reinterpret_cast<const float4*>(xp + (size_t)c * NN + 4);
    float xs[8] = {x0.x, x0.y, x0.z, x0.w, x1.x, x1.y, x1.z, x1.w};
#pragma unroll
    for (int ci = 0; ci < TCO; ++ci) {
      float w = lw[ci][c];
#pragma unroll
      for (int i = 0; i < 8; ++i) acc[ci][i] += w * xs[i];
    }
  }
#pragma unroll
  for (int ci = 0; ci < TCO; ++ci) {
    bf16* op = out + ((size_t)b * Co + co0 + ci) * NN + n0;
#pragma unroll
    for (int i = 0; i < 8; ++i) op[i] = __float2bfloat16(acc[ci][i]);
  }
}

// ---------------------------------------------------------------------------
// 1x1 conv with TRANSPOSED bf16 output [n][cq] (MFMA A/B-operand friendly).
// Used for q and k (Co = 64). grid: (NN/2048, CQ/TCO, NB), block 256.
// ---------------------------------------------------------------------------
__global__ __launch_bounds__(256) void proj_t(
    const float* __restrict__ X, const float* __restrict__ Wf,
    const float* __restrict__ bias, bf16* __restrict__ out) {
  __shared__ float lw[TCO][NC];
  __shared__ float lb[TCO];
  int b = blockIdx.z, co0 = blockIdx.y * TCO, tid = threadIdx.x;

  for (int idx = tid; idx < TCO * NC; idx += 256) {
    int r = idx >> 9, c = idx & (NC - 1);
    lw[r][c] = Wf[(size_t)(co0 + r) * NC + c];
  }
  if (tid < TCO) lb[tid] = bias[co0 + tid];
  __syncthreads();

  int n0 = (blockIdx.x * 256 + tid) * 8;
  const float* xp = X + (size_t)b * NC * NN + n0;

  float acc[TCO][8];
#pragma unroll
  for (int ci = 0; ci < TCO; ++ci)
#pragma unroll
    for (int i = 0; i < 8; ++i) acc[ci][i] = lb[ci];

#pragma unroll 2
  for (int c = 0; c < NC; ++c) {
    float4 x0 = *reinterpret_cast<const float4*>(xp + (size_t)c * NN);
    float4 x1 = *reinterpret_cast<const float4*>(xp + (size_t)c * NN + 4);
    float xs[8] = {x0.x, x0.y, x0.z, x0.w, x1.x, x1.y, x1.z, x1.w};
#pragma unroll
    for (int ci = 0; ci < TCO; ++ci) {
      float w = lw[ci][c];
#pragma unroll
      for (int i = 0; i < 8; ++i) acc[ci][i] += w * xs[i];
    }
  }
  // transposed write: out[(b*NN + n0+i)*CQ + co0 .. +7] packed as 16B
#pragma unroll
  for (int i = 0; i < 8; ++i) {
    bf16 tmp[8];
#pragma unroll
    for (int ci = 0; ci < TCO; ++ci) tmp[ci] = __float2bfloat16(acc[ci][i]);
    *reinterpret_cast<uint4*>(out + ((size_t)b * NN + n0 + i) * CQ + co0) =
        *reinterpret_cast<const uint4*>(tmp);
  }
}

// ---------------------------------------------------------------------------
// Flash attention, MFMA. One block = (batch b, 32-query tile n0).
// 4 waves; wave w owns channels [128w, 128w+128) (4 c-tiles of 32).
// Per m-tile (64 keys): S^T = K·Q^T via 8 MFMAs (n on lanes, m on regs ->
// per-lane softmax), P -> LDS (bf16), PV += V·P via 16 MFMAs/wave.
// grid: (NN/32, NB), block 256.
// ---------------------------------------------------------------------------
__global__ __launch_bounds__(256) void attn_flash(
    const bf16* __restrict__ qt, const bf16* __restrict__ kt,
    const bf16* __restrict__ vf, const float* __restrict__ x,
    const float* __restrict__ gamma, float* __restrict__ out0) {
  __shared__ bf16 qlds[32 * LP];
  __shared__ bf16 plds[32 * LP];
  int tid = threadIdx.x, lane = tid & 63, wave = tid >> 6;
  int b = blockIdx.y, n0 = blockIdx.x * 32;
  int col = lane & 31, half = lane >> 5;
  const float L2E = 1.44269504f;

  // stage Q tile [32][64] -> qlds
  {
    int r = tid >> 3, s = tid & 7;
    *reinterpret_cast<uint4*>(qlds + r * LP + s * 8) =
        *reinterpret_cast<const uint4*>(qt + ((size_t)b * NN + n0 + r) * CQ + s * 8);
  }
  __syncthreads();

  // B-operand fragments of Q^T (constant across m-tiles)
  short8 qfrag[4];
#pragma unroll
  for (int ks = 0; ks < 4; ++ks)
    qfrag[ks] = *reinterpret_cast<const short8*>(qlds + col * LP + ks * 16 + half * 8);

  floatx16 acc[4];
#pragma unroll
  for (int t = 0; t < 4; ++t) acc[t] = (floatx16)(0.f);
  float run_max = -3.0e38f, run_sum = 0.f;

  const bf16* kb = kt + (size_t)b * NN * CQ;
  const bf16* vb = vf + (size_t)b * NC * NN + (size_t)(wave * 128 + col) * NN;

  for (int mt = 0; mt < 64; ++mt) {
    int m0 = mt * 64;
    // ---- S^T tile: D[m][n] = K[m][cq] · Q^T[cq][n] --------------------
    floatx16 s0 = (floatx16)(0.f), s1 = (floatx16)(0.f);
    const bf16* kp = kb + (size_t)(m0 + col) * CQ + half * 8;
#pragma unroll
    for (int ks = 0; ks < 4; ++ks) {
      short8 a0 = *reinterpret_cast<const short8*>(kp + ks * 16);
      short8 a1 = *reinterpret_cast<const short8*>(kp + 32 * CQ + ks * 16);
      s0 = MFMA32(a0, qfrag[ks], s0, 0, 0, 0);
      s1 = MFMA32(a1, qfrag[ks], s1, 0, 0, 0);
    }
    // ---- online softmax (col n per lane; m on regs + lane-half) -------
    float tmax = s0[0];
#pragma unroll
    for (int r = 1; r < 16; ++r) tmax = fmaxf(tmax, s0[r]);
#pragma unroll
    for (int r = 0; r < 16; ++r) tmax = fmaxf(tmax, s1[r]);
    tmax = fmaxf(tmax, __shfl_xor(tmax, 32));
    float nmax = fmaxf(run_max, tmax);
    float alpha = exp2f((run_max - nmax) * L2E);
    run_max = nmax;
    float p0[16], p1[16], tsum = 0.f;
#pragma unroll
    for (int r = 0; r < 16; ++r) {
      p0[r] = exp2f((s0[r] - nmax) * L2E);
      p1[r] = exp2f((s1[r] - nmax) * L2E);
      tsum += p0[r] + p1[r];
    }
    run_sum = run_sum * alpha + tsum;
    __syncthreads();  // all waves done reading plds (previous PV)
#pragma unroll
    for (int r = 0; r < 16; r += 2) {
      int ml = (r & 3) + 8 * (r >> 2) + 4 * half;  // consecutive pair m, m+1
      *reinterpret_cast<bf162*>(plds + col * LP + ml) =
          __float22bfloat162_rn(make_float2(p0[r], p0[r + 1]));
      *reinterpret_cast<bf162*>(plds + col * LP + 32 + ml) =
          __float22bfloat162_rn(make_float2(p1[r], p1[r + 1]));
    }
    if (__any(alpha < 1.f)) {
#pragma unroll
      for (int t = 0; t < 4; ++t)
#pragma unroll
        for (int r = 0; r < 16; ++r) acc[t][r] *= alpha;
    }
    __syncthreads();  // P visible
    // ---- PV: D[c][n] += V[c][m] · P^T[m][n] ---------------------------
    const bf16* vp = vb + m0 + half * 8;
#pragma unroll
    for (int ks = 0; ks < 4; ++ks) {
      short8 bfr = *reinterpret_cast<const short8*>(plds + col * LP + ks * 16 + half * 8);
#pragma unroll
      for (int t = 0; t < 4; ++t) {
        short8 a = *reinterpret_cast<const short8*>(vp + (size_t)t * 32 * NN + ks * 16);
        acc[t] = MFMA32(a, bfr, acc[t], 0, 0, 0);
      }
    }
  }
  // ---- epilogue: out = gamma/denom * acc + x -------------------------------
  run_sum += __shfl_xor(run_sum, 32);
  float scl = gamma[0] / run_sum;
  size_t base = (size_t)b * NC * NN + n0 + col;
#pragma unroll
  for (int t = 0; t < 4; ++t) {
    int cb = wave * 128 + t * 32 + 4 * half;
#pragma unroll
    for (int r = 0; r < 16; ++r) {
      int c = cb + (r & 3) + 8 * (r >> 2);
      size_t idx = base + (size_t)c * NN;
      out0[idx] = scl * acc[t][r] + x[idx];
    }
  }
}

// ---------------------------------------------------------------------------
// out1 = x flattened (exact fp32 copy), 4 elements / thread.
// ---------------------------------------------------------------------------
__global__ __launch_bounds__(256) void copy_x(const float* __restrict__ x,
                                              float* __restrict__ out1) {
  size_t i = ((size_t)blockIdx.x * 256 + threadIdx.x) * 4;
  *reinterpret_cast<float4*>(out1 + i) =
      *reinterpret_cast<const float4*>(x + i);
}

extern "C" void kernel_launch(void* const* d_in, const int* in_sizes, int n_in,
                              void* d_out, int out_size, void* d_ws,
                              size_t ws_size, hipStream_t stream) {
  const float* x     = (const float*)d_in[0];
  // d_in[1] = style (unused by the reference)
  const float* skel  = (const float*)d_in[2];
  const float* Wq    = (const float*)d_in[3];
  const float* bq    = (const float*)d_in[4];
  const float* Wk    = (const float*)d_in[5];
  const float* bk    = (const float*)d_in[6];
  const float* Wv    = (const float*)d_in[7];
  const float* bv    = (const float*)d_in[8];
  const float* gamma = (const float*)d_in[9];

  // ws (4 MB): qt [B][N][CQ] bf16 (2 MB) + kt [B][N][CQ] bf16 (2 MB).
  // vf [B][C][N] bf16 (16.8 MB) lives in the out1 half of d_out (33.5 MB);
  // attn reads vf / writes out0 only; copy_x overwrites out1 afterwards.
  bf16* qt = (bf16*)d_ws;
  bf16* kt = qt + (size_t)NB * NN * CQ;

  float* out0 = (float*)d_out;
  float* out1 = out0 + (size_t)NB * NC * NN;
  bf16*  vf   = (bf16*)out1;  // scratch until copy_x runs

  proj_t<<<dim3(2, CQ / TCO, NB), dim3(256), 0, stream>>>(x, Wq, bq, qt);
  proj_t<<<dim3(2, CQ / TCO, NB), dim3(256), 0, stream>>>(skel, Wk, bk, kt);
  proj_kernel<<<dim3(2, NC / TCO, NB), dim3(256), 0, stream>>>(skel, Wv, bv, vf, NC);
  attn_flash<<<dim3(NN / 32, NB), dim3(256), 0, stream>>>(qt, kt, vf, x, gamma, out0);
  copy_x<<<dim3(8192), dim3(256), 0, stream>>>(x, out1);
}

// Round 5
// 397.428 us; speedup vs baseline: 31.6285x; 2.7101x over previous
//
#include <hip/hip_runtime.h>
#include <hip/hip_bf16.h>

typedef __hip_bfloat16 bf16;
typedef __attribute__((ext_vector_type(8))) short short8;
typedef __attribute__((ext_vector_type(16))) float floatx16;

#define NB 4
#define NC 512
#define CQ 64
#define NN 4096
#define MFMA32 __builtin_amdgcn_mfma_f32_32x32x16_bf16

#define PQ 72   // qlds pitch (bf16): 144B rows, 16B aligned
#define PM 264  // plds pitch (bf16): 528B rows, 16B aligned, 132dw%32=4
#define PA 40   // proj W-tile pitch
#define PB 40   // proj X-tile pitch

// ---------------------------------------------------------------------------
// MFMA 1x1-conv GEMM: C[co][n] = W[co][c] * X[c][n] + bias.
// Tile 64co x 256n, BK=32. fp32 global -> bf16 LDS staging.
// m-tile 0 uses W0/b0 and writes TRANSPOSED outT[b][n][64] (q/k path);
// m-tiles >=1 use W1/b1 rows (mt-1)*64.. and write outV[b][co][n] (V path).
// grid: (16 n-tiles, m-tiles, NB), block 256.
// ---------------------------------------------------------------------------
__global__ __launch_bounds__(256) void proj_mfma(
    const float* __restrict__ X, const float* __restrict__ W0,
    const float* __restrict__ b0, const float* __restrict__ W1,
    const float* __restrict__ b1, bf16* __restrict__ outT,
    bf16* __restrict__ outV) {
  __shared__ bf16 At[64 * PA];
  __shared__ bf16 Bt[256 * PB];
  int tid = threadIdx.x, lane = tid & 63, wave = tid >> 6;
  int col = lane & 31, half = lane >> 5;
  int nt = blockIdx.x, mt = blockIdx.y, b = blockIdx.z;
  int nbase = nt * 256;
  const float* Wp = (mt == 0) ? W0 : W1 + (size_t)(mt - 1) * 64 * NC;
  const float* Xb = X + (size_t)b * NC * NN;

  floatx16 acc[2][2];
#pragma unroll
  for (int i = 0; i < 2; ++i)
#pragma unroll
    for (int j = 0; j < 2; ++j) acc[i][j] = (floatx16)(0.f);

  int wr = tid >> 2, wch = tid & 3;         // W staging: row, 8-wide k-chunk
  int xg = tid & 63, xc0 = (tid >> 6) * 8;  // X staging: n-group of 4, c-base

  for (int k0 = 0; k0 < NC; k0 += 32) {
    {  // stage W tile -> At[64][32]
      const float* wp = Wp + (size_t)wr * NC + k0 + wch * 8;
      float4 f0 = *(const float4*)(wp);
      float4 f1 = *(const float4*)(wp + 4);
      bf16 t8[8] = {__float2bfloat16(f0.x), __float2bfloat16(f0.y),
                    __float2bfloat16(f0.z), __float2bfloat16(f0.w),
                    __float2bfloat16(f1.x), __float2bfloat16(f1.y),
                    __float2bfloat16(f1.z), __float2bfloat16(f1.w)};
      *(uint4*)(At + wr * PA + wch * 8) = *(const uint4*)t8;
    }
    {  // stage X tile -> Bt[256][32] (transposed: [n][k])
      float xs[8][4];
#pragma unroll
      for (int cc = 0; cc < 8; ++cc) {
        float4 f = *(const float4*)(Xb + (size_t)(k0 + xc0 + cc) * NN + nbase + xg * 4);
        xs[cc][0] = f.x; xs[cc][1] = f.y; xs[cc][2] = f.z; xs[cc][3] = f.w;
      }
#pragma unroll
      for (int nn = 0; nn < 4; ++nn) {
        bf16 t8[8];
#pragma unroll
        for (int cc = 0; cc < 8; ++cc) t8[cc] = __float2bfloat16(xs[cc][nn]);
        *(uint4*)(Bt + (xg * 4 + nn) * PB + xc0) = *(const uint4*)t8;
      }
    }
    __syncthreads();
#pragma unroll
    for (int ks = 0; ks < 2; ++ks) {
      short8 a0 = *(const short8*)(At + col * PA + ks * 16 + half * 8);
      short8 a1 = *(const short8*)(At + (col + 32) * PA + ks * 16 + half * 8);
      short8 q0 = *(const short8*)(Bt + (wave * 64 + col) * PB + ks * 16 + half * 8);
      short8 q1 = *(const short8*)(Bt + (wave * 64 + 32 + col) * PB + ks * 16 + half * 8);
      acc[0][0] = MFMA32(a0, q0, acc[0][0], 0, 0, 0);
      acc[0][1] = MFMA32(a0, q1, acc[0][1], 0, 0, 0);
      acc[1][0] = MFMA32(a1, q0, acc[1][0], 0, 0, 0);
      acc[1][1] = MFMA32(a1, q1, acc[1][1], 0, 0, 0);
    }
    __syncthreads();
  }
  // epilogue: C/D layout col=lane&31 -> n, row=(r&3)+8*(r>>2)+4*half -> co
#pragma unroll
  for (int ms = 0; ms < 2; ++ms)
#pragma unroll
    for (int r = 0; r < 16; ++r) {
      int co = ms * 32 + (r & 3) + 8 * (r >> 2) + 4 * half;
      float bb = (mt == 0) ? b0[co] : b1[(mt - 1) * 64 + co];
#pragma unroll
      for (int ns = 0; ns < 2; ++ns) {
        int n = nbase + wave * 64 + ns * 32 + col;
        float v = acc[ms][ns][r] + bb;
        if (mt == 0)
          outT[((size_t)b * NN + n) * CQ + co] = __float2bfloat16(v);
        else
          outV[((size_t)b * NC + (mt - 1) * 64 + co) * NN + n] = __float2bfloat16(v);
      }
    }
}

// ---------------------------------------------------------------------------
// Cooperative MFMA flash attention. Block = (batch, 64 queries), 4 waves.
// Per 256-m chunk: wave w computes S^T for its own 64-m subtile (16 MFMA),
// softmax max/sum shared across waves via LDS (2 barriers/chunk), P tile in
// LDS (single buffer, pitch 264), then each wave does PV for its 128
// channels (128 MFMA). acc[4 c-tiles][2 n-sub] = 128 VGPRs.
// grid: (NN/64, NB), block 256.
// ---------------------------------------------------------------------------
__global__ __launch_bounds__(256) void attn_flash(
    const bf16* __restrict__ qt, const bf16* __restrict__ kt,
    const bf16* __restrict__ vf, const float* __restrict__ x,
    const float* __restrict__ gamma, float* __restrict__ out0) {
  __shared__ bf16 qlds[64 * PQ];
  __shared__ bf16 plds[64 * PM];
  __shared__ float lred[4][2][32];
  __shared__ float sred[4][2][32];
  int tid = threadIdx.x, lane = tid & 63, wave = tid >> 6;
  int col = lane & 31, half = lane >> 5;
  int b = blockIdx.y, n0 = blockIdx.x * 64;
  const float L2E = 1.44269504f;

  // stage Q tile [64 n][64 cq]
#pragma unroll
  for (int i = 0; i < 2; ++i) {
    int cid = tid * 2 + i;
    int r = cid >> 3, ch = cid & 7;
    *(uint4*)(qlds + r * PQ + ch * 8) =
        *(const uint4*)(qt + ((size_t)b * NN + n0 + r) * CQ + ch * 8);
  }
  __syncthreads();

  floatx16 acc[4][2];
#pragma unroll
  for (int t = 0; t < 4; ++t)
#pragma unroll
    for (int ns = 0; ns < 2; ++ns) acc[t][ns] = (floatx16)(0.f);
  float run_max[2] = {-3.0e38f, -3.0e38f}, run_sum[2] = {0.f, 0.f};

  const bf16* kb = kt + (size_t)b * NN * CQ;
  const bf16* vb = vf + (size_t)b * NC * NN + (size_t)(wave * 128 + col) * NN;

  for (int it = 0; it < 16; ++it) {
    int m0 = it * 256;
    int mw = m0 + wave * 64;
    // ---- S^T for this wave's 64-m subtile: D[m][n], n on lanes ----------
    floatx16 s[2][2];
#pragma unroll
    for (int i = 0; i < 2; ++i)
#pragma unroll
      for (int j = 0; j < 2; ++j) s[i][j] = (floatx16)(0.f);
    const bf16* kp = kb + (size_t)(mw + col) * CQ + half * 8;
#pragma unroll
    for (int ks = 0; ks < 4; ++ks) {
      short8 a0 = *(const short8*)(kp + ks * 16);
      short8 a1 = *(const short8*)(kp + (size_t)32 * CQ + ks * 16);
      short8 q0 = *(const short8*)(qlds + col * PQ + ks * 16 + half * 8);
      short8 q1 = *(const short8*)(qlds + (32 + col) * PQ + ks * 16 + half * 8);
      s[0][0] = MFMA32(a0, q0, s[0][0], 0, 0, 0);
      s[0][1] = MFMA32(a0, q1, s[0][1], 0, 0, 0);
      s[1][0] = MFMA32(a1, q0, s[1][0], 0, 0, 0);
      s[1][1] = MFMA32(a1, q1, s[1][1], 0, 0, 0);
    }
    // ---- wave-local max over its 64 m, publish ---------------------------
#pragma unroll
    for (int ns = 0; ns < 2; ++ns) {
      float lm = s[0][ns][0];
#pragma unroll
      for (int r = 1; r < 16; ++r) lm = fmaxf(lm, s[0][ns][r]);
#pragma unroll
      for (int r = 0; r < 16; ++r) lm = fmaxf(lm, s[1][ns][r]);
      lm = fmaxf(lm, __shfl_xor(lm, 32));
      if (half == 0) lred[wave][ns][col] = lm;
    }
    __syncthreads();  // A: lmax visible; also orders prev-iter PV before P-write
    float nm[2], alpha[2];
#pragma unroll
    for (int ns = 0; ns < 2; ++ns) {
      float m4 = fmaxf(fmaxf(lred[0][ns][col], lred[1][ns][col]),
                       fmaxf(lred[2][ns][col], lred[3][ns][col]));
      nm[ns] = fmaxf(run_max[ns], m4);
      alpha[ns] = exp2f((run_max[ns] - nm[ns]) * L2E);
      run_max[ns] = nm[ns];
    }
    // ---- P = exp(S - nm), write LDS [n][m-chunk 256], partial sums -------
    float psum[2] = {0.f, 0.f};
#pragma unroll
    for (int ms = 0; ms < 2; ++ms)
#pragma unroll
      for (int ns = 0; ns < 2; ++ns) {
        float pv[16];
#pragma unroll
        for (int r = 0; r < 16; ++r) {
          pv[r] = exp2f((s[ms][ns][r] - nm[ns]) * L2E);
          psum[ns] += pv[r];
        }
        bf16* pw = plds + (ns * 32 + col) * PM + wave * 64 + ms * 32 + 4 * half;
#pragma unroll
        for (int rg = 0; rg < 4; ++rg) {  // m = .. + rg*8 + {0,1,2,3}
          bf16 t4[4] = {__float2bfloat16(pv[4 * rg]), __float2bfloat16(pv[4 * rg + 1]),
                        __float2bfloat16(pv[4 * rg + 2]), __float2bfloat16(pv[4 * rg + 3])};
          *(uint2*)(pw + rg * 8) = *(const uint2*)t4;
        }
      }
#pragma unroll
    for (int ns = 0; ns < 2; ++ns) {
      float ps = psum[ns] + __shfl_xor(psum[ns], 32);
      if (half == 0) sred[wave][ns][col] = ps;
    }
    if (__any((alpha[0] < 1.f) || (alpha[1] < 1.f))) {
#pragma unroll
      for (int t = 0; t < 4; ++t)
#pragma unroll
        for (int ns = 0; ns < 2; ++ns)
#pragma unroll
          for (int r = 0; r < 16; ++r) acc[t][ns][r] *= alpha[ns];
    }
    __syncthreads();  // B: P + psums visible
#pragma unroll
    for (int ns = 0; ns < 2; ++ns)
      run_sum[ns] = run_sum[ns] * alpha[ns] +
                    (sred[0][ns][col] + sred[1][ns][col] +
                     sred[2][ns][col] + sred[3][ns][col]);
    // ---- PV over full 256-m chunk: D[c][n] += V[c][m] P^T[m][n] ----------
    const bf16* vp = vb + m0 + half * 8;
#pragma unroll 4
    for (int ki = 0; ki < 16; ++ki) {
      short8 p0 = *(const short8*)(plds + col * PM + ki * 16 + half * 8);
      short8 p1 = *(const short8*)(plds + (32 + col) * PM + ki * 16 + half * 8);
#pragma unroll
      for (int t = 0; t < 4; ++t) {
        short8 av = *(const short8*)(vp + (size_t)t * 32 * NN + ki * 16);
        acc[t][0] = MFMA32(av, p0, acc[t][0], 0, 0, 0);
        acc[t][1] = MFMA32(av, p1, acc[t][1], 0, 0, 0);
      }
    }
  }
  // ---- epilogue: out0 = gamma/denom * acc + x ----------------------------
  float g = gamma[0];
  float scl[2] = {g / run_sum[0], g / run_sum[1]};
#pragma unroll
  for (int t = 0; t < 4; ++t)
#pragma unroll
    for (int r = 0; r < 16; ++r) {
      int c = wave * 128 + t * 32 + (r & 3) + 8 * (r >> 2) + 4 * half;
      size_t rowb = (size_t)b * NC * NN + (size_t)c * NN + n0 + col;
#pragma unroll
      for (int ns = 0; ns < 2; ++ns) {
        size_t idx = rowb + ns * 32;
        out0[idx] = scl[ns] * acc[t][ns][r] + x[idx];
      }
    }
}

// ---------------------------------------------------------------------------
// out1 = x flattened (exact fp32 copy), 4 elements / thread.
// ---------------------------------------------------------------------------
__global__ __launch_bounds__(256) void copy_x(const float* __restrict__ x,
                                              float* __restrict__ out1) {
  size_t i = ((size_t)blockIdx.x * 256 + threadIdx.x) * 4;
  *reinterpret_cast<float4*>(out1 + i) =
      *reinterpret_cast<const float4*>(x + i);
}

extern "C" void kernel_launch(void* const* d_in, const int* in_sizes, int n_in,
                              void* d_out, int out_size, void* d_ws,
                              size_t ws_size, hipStream_t stream) {
  const float* x     = (const float*)d_in[0];
  // d_in[1] = style (unused by the reference)
  const float* skel  = (const float*)d_in[2];
  const float* Wq    = (const float*)d_in[3];
  const float* bq    = (const float*)d_in[4];
  const float* Wk    = (const float*)d_in[5];
  const float* bk    = (const float*)d_in[6];
  const float* Wv    = (const float*)d_in[7];
  const float* bv    = (const float*)d_in[8];
  const float* gamma = (const float*)d_in[9];

  // ws (4 MB): qt [B][N][64] bf16 + kt [B][N][64] bf16.
  // vf [B][C][N] bf16 (16.8 MB) lives in the out1 half of d_out; attn reads
  // vf / writes out0 only; copy_x overwrites out1 afterwards (stream order).
  bf16* qt = (bf16*)d_ws;
  bf16* kt = qt + (size_t)NB * NN * CQ;

  float* out0 = (float*)d_out;
  float* out1 = out0 + (size_t)NB * NC * NN;
  bf16*  vf   = (bf16*)out1;  // scratch until copy_x runs

  // q projection: M=64 (mt 0 only -> writes qt transposed)
  proj_mfma<<<dim3(16, 1, NB), dim3(256), 0, stream>>>(x, Wq, bq, Wv, bv, qt, vf);
  // fused k+v projection over skel: stacked M=576 (mt0 -> kt, mt1..8 -> vf)
  proj_mfma<<<dim3(16, 9, NB), dim3(256), 0, stream>>>(skel, Wk, bk, Wv, bv, kt, vf);
  attn_flash<<<dim3(NN / 64, NB), dim3(256), 0, stream>>>(qt, kt, vf, x, gamma, out0);
  copy_x<<<dim3(8192), dim3(256), 0, stream>>>(x, out1);
}